// Round 17
// baseline (437.539 us; speedup 1.0000x reference)
//
#include <hip/hip_runtime.h>
#include <hip/hip_fp16.h>

#define NN 100000
#define NE 1200000
#define DIN 128
#define DH 64
#define DOUT_FINAL 47
#define NPB2 8       // nodes per block in gather kernels (2 per wave)
#define MT 128       // GEMM m-tile
#define NBKT 391     // (NN + 255) >> 8  — bucket = dst >> 8 (256 nodes/bucket)
#define EB 4096      // edges per block in scatter_pairs_k

// ---------------- binned CSR build ----------------

__global__ void bucket_hist_k(const int* __restrict__ dst, int* __restrict__ bktCnt) {
    __shared__ int h[NBKT];
    int tid = threadIdx.x;
    for (int i = tid; i < NBKT; i += 256) h[i] = 0;
    __syncthreads();
    for (int e = blockIdx.x * 256 + tid; e < NE; e += gridDim.x * 256)
        atomicAdd(&h[dst[e] >> 8], 1);
    __syncthreads();
    for (int i = tid; i < NBKT; i += 256)
        if (h[i]) atomicAdd(&bktCnt[i], h[i]);
}

__global__ void bscan_k(const int* __restrict__ bktCnt, int* __restrict__ bktPtr) {
    __shared__ int s[512];
    int tid = threadIdx.x;
    int v = (tid < NBKT) ? bktCnt[tid] : 0;
    s[tid] = v;
    __syncthreads();
    for (int off = 1; off < 512; off <<= 1) {
        int t = (tid >= off) ? s[tid - off] : 0;
        __syncthreads();
        s[tid] += t;
        __syncthreads();
    }
    if (tid < NBKT) bktPtr[tid] = s[tid] - v;
    if (tid == 0) bktPtr[NBKT] = NE;
}

__global__ void scatter_pairs_k(const int* __restrict__ src, const int* __restrict__ dst,
                                const int* __restrict__ bktPtr, int* __restrict__ bktCur,
                                int2* __restrict__ pairs) {
    __shared__ int h[NBKT];
    __shared__ int base[NBKT];
    __shared__ int cur[NBKT];
    int tid = threadIdx.x;
    int e0 = blockIdx.x * EB;
    int e1 = e0 + EB < NE ? e0 + EB : NE;
    for (int i = tid; i < NBKT; i += 256) { h[i] = 0; cur[i] = 0; }
    __syncthreads();
    for (int e = e0 + tid; e < e1; e += 256)
        atomicAdd(&h[dst[e] >> 8], 1);
    __syncthreads();
    for (int i = tid; i < NBKT; i += 256) {
        int c = h[i];
        base[i] = bktPtr[i] + (c ? atomicAdd(&bktCur[i], c) : 0);
    }
    __syncthreads();
    for (int e = e0 + tid; e < e1; e += 256) {
        int d = dst[e];
        int b = d >> 8;
        int p = base[b] + atomicAdd(&cur[b], 1);
        pairs[p] = make_int2(src[e], d);
    }
}

__global__ void count_node_k(const int2* __restrict__ pairs, const int* __restrict__ bktPtr,
                             int* __restrict__ cnt) {
    __shared__ int h[256];
    int tid = threadIdx.x;
    int b = blockIdx.x;
    h[tid] = 0;
    __syncthreads();
    int e1 = bktPtr[b + 1];
    for (int e = bktPtr[b] + tid; e < e1; e += 256)
        atomicAdd(&h[pairs[e].y & 255], 1);
    __syncthreads();
    int node = (b << 8) + tid;
    if (node < NN) cnt[node] = h[tid];
}

__global__ void scan1_k(const int* __restrict__ cnt, int* __restrict__ ptr,
                        int* __restrict__ bsum, float* __restrict__ dinv) {
    __shared__ int s[256];
    int tid = threadIdx.x;
    int i = blockIdx.x * 256 + tid;
    int v = (i < NN) ? cnt[i] : 0;
    s[tid] = v;
    __syncthreads();
    for (int off = 1; off < 256; off <<= 1) {
        int t = (tid >= off) ? s[tid - off] : 0;
        __syncthreads();
        s[tid] += t;
        __syncthreads();
    }
    if (i < NN) {
        ptr[i] = s[tid] - v;
        dinv[i] = (v > 0) ? 1.0f / (float)v : 0.0f;
    }
    if (tid == 255) bsum[blockIdx.x] = s[255];
}

__global__ void scan2_k(int* __restrict__ bsum, int nb) {
    __shared__ int s[512];
    int tid = threadIdx.x;
    int v = (tid < nb) ? bsum[tid] : 0;
    s[tid] = v;
    __syncthreads();
    for (int off = 1; off < 512; off <<= 1) {
        int t = (tid >= off) ? s[tid - off] : 0;
        __syncthreads();
        s[tid] += t;
        __syncthreads();
    }
    if (tid < nb) bsum[tid] = s[tid] - v;
}

__global__ void scan3_k(int* __restrict__ ptr, const int* __restrict__ bsum) {
    int i = blockIdx.x * 256 + threadIdx.x;
    if (i < NN) ptr[i] += bsum[blockIdx.x];
    if (i == 0) ptr[NN] = NE;
}

__global__ void fill_bucket_k(const int2* __restrict__ pairs, const int* __restrict__ bktPtr,
                              const int* __restrict__ ptr, int* __restrict__ csrc) {
    __shared__ int cur[256];
    __shared__ int sptr[256];
    int tid = threadIdx.x;
    int b = blockIdx.x;
    cur[tid] = 0;
    int node = (b << 8) + tid;
    sptr[tid] = (node < NN) ? ptr[node] : 0;
    __syncthreads();
    int e1 = bktPtr[b + 1];
    for (int e = bktPtr[b] + tid; e < e1; e += 256) {
        int2 pr = pairs[e];
        int lo = pr.y & 255;
        int r = atomicAdd(&cur[lo], 1);
        csrc[sptr[lo] + r] = pr.x;
    }
}

// ---------------- input projection GEMM (K=128): hinp(fp16) = x@Win^T + bin; xa(fp32) = relu ----------------

__global__ __launch_bounds__(512) void gemm_in_k(const float* __restrict__ X,
                                                 const float* __restrict__ W,
                                                 const float* __restrict__ bias,
                                                 __half* __restrict__ hinph,
                                                 float* __restrict__ xa) {
    __shared__ float xs[MT * 72];
    __shared__ float ws_[64 * 64];
    const int t = threadIdx.x;
    const int mBase = blockIdx.x * MT;
    const int ty = t >> 3;
    const int tx = t & 7;

    float acc[2][8];
    #pragma unroll
    for (int i = 0; i < 2; ++i)
        #pragma unroll
        for (int j = 0; j < 8; ++j) acc[i][j] = 0.0f;

    for (int kc = 0; kc < 128; kc += 64) {
        {
            int r0 = t >> 4;
            int c4 = t & 15;
            #pragma unroll
            for (int rep = 0; rep < 4; ++rep) {
                int r = r0 + rep * 32;
                int gm = mBase + r;
                float4 v = make_float4(0.f, 0.f, 0.f, 0.f);
                if (gm < NN) v = *(const float4*)&X[(size_t)gm * 128 + kc + c4 * 4];
                *(float4*)&xs[r * 72 + c4 * 4] = v;
            }
        }
        {
            int n = t >> 3;
            int c0 = t & 7;
            #pragma unroll
            for (int rep = 0; rep < 2; ++rep) {
                int c4 = c0 + rep * 8;
                float4 v = *(const float4*)&W[(size_t)n * 128 + kc + c4 * 4];
                ws_[(c4 * 4 + 0) * 64 + n] = v.x;
                ws_[(c4 * 4 + 1) * 64 + n] = v.y;
                ws_[(c4 * 4 + 2) * 64 + n] = v.z;
                ws_[(c4 * 4 + 3) * 64 + n] = v.w;
            }
        }
        __syncthreads();
        #pragma unroll 4
        for (int kk = 0; kk < 16; ++kk) {
            float4 a[2];
            #pragma unroll
            for (int i = 0; i < 2; ++i)
                a[i] = *(const float4*)&xs[(ty + 64 * i) * 72 + kk * 4];
            #pragma unroll
            for (int p = 0; p < 4; ++p) {
                float4 b0 = *(const float4*)&ws_[(kk * 4 + p) * 64 + tx * 8];
                float4 b1 = *(const float4*)&ws_[(kk * 4 + p) * 64 + tx * 8 + 4];
                #pragma unroll
                for (int i = 0; i < 2; ++i) {
                    float av = (&a[i].x)[p];
                    acc[i][0] += av * b0.x; acc[i][1] += av * b0.y;
                    acc[i][2] += av * b0.z; acc[i][3] += av * b0.w;
                    acc[i][4] += av * b1.x; acc[i][5] += av * b1.y;
                    acc[i][6] += av * b1.z; acc[i][7] += av * b1.w;
                }
            }
        }
        __syncthreads();
    }

    #pragma unroll
    for (int i = 0; i < 2; ++i) {
        int m = mBase + ty + 64 * i;
        if (m >= NN) continue;
        int n0 = tx * 8;
        union { __half h[8]; uint4 u; } pk;
        #pragma unroll
        for (int j = 0; j < 8; ++j) {
            float v = acc[i][j] + bias[n0 + j];
            pk.h[j] = __float2half(v);
            xa[(size_t)m * 64 + n0 + j] = fmaxf(v, 0.0f);
        }
        *(uint4*)&hinph[(size_t)m * 64 + n0] = pk.u;
    }
}

// ---------------- fused dual GEMM (K=64): yl(fp16) = X@Wl^T ; yr(fp16) = X@Wr^T ----------------

__global__ __launch_bounds__(512) void gemm_dual_k(const float* __restrict__ X,
                                                   const float* __restrict__ Wl,
                                                   const float* __restrict__ Wr,
                                                   __half* __restrict__ ylh,
                                                   __half* __restrict__ yrh,
                                                   int dout) {
    __shared__ float xs[MT * 72];
    __shared__ float ws_[64 * 64];
    const int t = threadIdx.x;
    const int mBase = blockIdx.x * MT;
    const int ty = t >> 3;
    const int tx = t & 7;

    {
        int r0 = t >> 4;
        int c4 = t & 15;
        #pragma unroll
        for (int rep = 0; rep < 4; ++rep) {
            int r = r0 + rep * 32;
            int gm = mBase + r;
            float4 v = make_float4(0.f, 0.f, 0.f, 0.f);
            if (gm < NN) v = *(const float4*)&X[(size_t)gm * 64 + c4 * 4];
            *(float4*)&xs[r * 72 + c4 * 4] = v;
        }
    }

    float accL[2][8], accR[2][8];
    #pragma unroll
    for (int i = 0; i < 2; ++i)
        #pragma unroll
        for (int j = 0; j < 8; ++j) { accL[i][j] = 0.0f; accR[i][j] = 0.0f; }

    // ---- pass 1: Wl ----
    {
        int n = t >> 3;
        int c0 = t & 7;
        #pragma unroll
        for (int rep = 0; rep < 2; ++rep) {
            int c4 = c0 + rep * 8;
            float4 v = make_float4(0.f, 0.f, 0.f, 0.f);
            if (n < dout) v = *(const float4*)&Wl[(size_t)n * 64 + c4 * 4];
            ws_[(c4 * 4 + 0) * 64 + n] = v.x;
            ws_[(c4 * 4 + 1) * 64 + n] = v.y;
            ws_[(c4 * 4 + 2) * 64 + n] = v.z;
            ws_[(c4 * 4 + 3) * 64 + n] = v.w;
        }
    }
    __syncthreads();
    #pragma unroll 4
    for (int kk = 0; kk < 16; ++kk) {
        float4 a[2];
        #pragma unroll
        for (int i = 0; i < 2; ++i)
            a[i] = *(const float4*)&xs[(ty + 64 * i) * 72 + kk * 4];
        #pragma unroll
        for (int p = 0; p < 4; ++p) {
            float4 b0 = *(const float4*)&ws_[(kk * 4 + p) * 64 + tx * 8];
            float4 b1 = *(const float4*)&ws_[(kk * 4 + p) * 64 + tx * 8 + 4];
            #pragma unroll
            for (int i = 0; i < 2; ++i) {
                float av = (&a[i].x)[p];
                accL[i][0] += av * b0.x; accL[i][1] += av * b0.y;
                accL[i][2] += av * b0.z; accL[i][3] += av * b0.w;
                accL[i][4] += av * b1.x; accL[i][5] += av * b1.y;
                accL[i][6] += av * b1.z; accL[i][7] += av * b1.w;
            }
        }
    }
    __syncthreads();
    // ---- pass 2: Wr ----
    {
        int n = t >> 3;
        int c0 = t & 7;
        #pragma unroll
        for (int rep = 0; rep < 2; ++rep) {
            int c4 = c0 + rep * 8;
            float4 v = make_float4(0.f, 0.f, 0.f, 0.f);
            if (n < dout) v = *(const float4*)&Wr[(size_t)n * 64 + c4 * 4];
            ws_[(c4 * 4 + 0) * 64 + n] = v.x;
            ws_[(c4 * 4 + 1) * 64 + n] = v.y;
            ws_[(c4 * 4 + 2) * 64 + n] = v.z;
            ws_[(c4 * 4 + 3) * 64 + n] = v.w;
        }
    }
    __syncthreads();
    #pragma unroll 4
    for (int kk = 0; kk < 16; ++kk) {
        float4 a[2];
        #pragma unroll
        for (int i = 0; i < 2; ++i)
            a[i] = *(const float4*)&xs[(ty + 64 * i) * 72 + kk * 4];
        #pragma unroll
        for (int p = 0; p < 4; ++p) {
            float4 b0 = *(const float4*)&ws_[(kk * 4 + p) * 64 + tx * 8];
            float4 b1 = *(const float4*)&ws_[(kk * 4 + p) * 64 + tx * 8 + 4];
            #pragma unroll
            for (int i = 0; i < 2; ++i) {
                float av = (&a[i].x)[p];
                accR[i][0] += av * b0.x; accR[i][1] += av * b0.y;
                accR[i][2] += av * b0.z; accR[i][3] += av * b0.w;
                accR[i][4] += av * b1.x; accR[i][5] += av * b1.y;
                accR[i][6] += av * b1.z; accR[i][7] += av * b1.w;
            }
        }
    }

    #pragma unroll
    for (int i = 0; i < 2; ++i) {
        int m = mBase + ty + 64 * i;
        if (m >= NN) continue;
        int n0 = tx * 8;
        union { __half h[8]; uint4 u; } pl, pr;
        #pragma unroll
        for (int j = 0; j < 8; ++j) {
            pl.h[j] = __float2half(accL[i][j]);
            pr.h[j] = __float2half(accR[i][j]);
        }
        *(uint4*)&ylh[(size_t)m * 64 + n0] = pl.u;
        *(uint4*)&yrh[(size_t)m * 64 + n0] = pr.u;
    }
}

// ---------------- gather core: ONE NODE PER 32-LANE HALF-WAVE ----------------
// fl = lane&31 handles features {2fl, 2fl+1} (32 lanes x 4B = one 128B row).
// All shuffles width=32 -> halves fully independent (2 latency chains/wave,
// divergent trip counts safe: bpermute sources stay inside the active half).
// Up to 8 guarded loads in flight per batch.

__device__ __forceinline__ float2 gather_half(const __half* __restrict__ ylh,
                                              const int* __restrict__ csrc,
                                              int eb, int ee, int fl) {
    const char* base = (const char*)ylh;
    int fo = fl * 4;
    float ax = 0.0f, ay = 0.0f;
    for (int e0 = eb; e0 < ee; e0 += 32) {
        int rem = ee - e0;
        int m = rem < 32 ? rem : 32;
        int sv = (fl < m) ? csrc[e0 + fl] : 0;
        for (int j = 0; j < m; j += 8) {
            int s0 = __shfl(sv, j + 0, 32), s1 = __shfl(sv, j + 1, 32);
            int s2 = __shfl(sv, j + 2, 32), s3 = __shfl(sv, j + 3, 32);
            int s4 = __shfl(sv, j + 4, 32), s5 = __shfl(sv, j + 5, 32);
            int s6 = __shfl(sv, j + 6, 32), s7 = __shfl(sv, j + 7, 32);
            int r = m - j;  // >=1, half-uniform
            float2 f;
            f = __half22float2(*(const __half2*)(base + (s0 * 128 + fo))); ax += f.x; ay += f.y;
            if (r > 1) { f = __half22float2(*(const __half2*)(base + (s1 * 128 + fo))); ax += f.x; ay += f.y; }
            if (r > 2) { f = __half22float2(*(const __half2*)(base + (s2 * 128 + fo))); ax += f.x; ay += f.y; }
            if (r > 3) { f = __half22float2(*(const __half2*)(base + (s3 * 128 + fo))); ax += f.x; ay += f.y; }
            if (r > 4) { f = __half22float2(*(const __half2*)(base + (s4 * 128 + fo))); ax += f.x; ay += f.y; }
            if (r > 5) { f = __half22float2(*(const __half2*)(base + (s5 * 128 + fo))); ax += f.x; ay += f.y; }
            if (r > 6) { f = __half22float2(*(const __half2*)(base + (s6 * 128 + fo))); ax += f.x; ay += f.y; }
            if (r > 7) { f = __half22float2(*(const __half2*)(base + (s7 * 128 + fo))); ax += f.x; ay += f.y; }
        }
    }
    return make_float2(ax, ay);
}

// ---------------- mid-layer aggregate: relu + residual (yr/hinp fp16) ----------------

__global__ void aggregate_mid_k(const __half* __restrict__ ylh, const __half* __restrict__ yrh,
                                const __half* __restrict__ hinph,
                                const int* __restrict__ ptr, const int* __restrict__ csrc,
                                const float* __restrict__ dinv, const float* __restrict__ bl,
                                float* __restrict__ outp) {
    int tid = threadIdx.x;
    int w = tid >> 6, lane = tid & 63;
    int half = lane >> 5, fl = lane & 31;
    int i = blockIdx.x * NPB2 + w * 2 + half;
    if (i >= NN) return;
    float2 acc = gather_half(ylh, csrc, ptr[i], ptr[i + 1], fl);
    int f0 = fl * 2;
    float dv = dinv[i];
    float2 yrv = __half22float2(*(const __half2*)&yrh[(size_t)i * 64 + f0]);
    float2 blv = *(const float2*)&bl[f0];
    float2 hv = __half22float2(*(const __half2*)&hinph[(size_t)i * 64 + f0]);
    float2 r;
    r.x = fmaxf(acc.x * dv + yrv.x + blv.x, 0.0f) + 0.2f * hv.x;
    r.y = fmaxf(acc.y * dv + yrv.y + blv.y, 0.0f) + 0.2f * hv.y;
    *(float2*)&outp[(size_t)i * 64 + f0] = r;
}

// ---------------- final aggregate fused with log_softmax (yr fp16) ----------------

__global__ void aggregate_final_k(const __half* __restrict__ ylh, const __half* __restrict__ yrh,
                                  const int* __restrict__ ptr, const int* __restrict__ csrc,
                                  const float* __restrict__ dinv, const float* __restrict__ bl,
                                  float* __restrict__ outp) {
    int tid = threadIdx.x;
    int w = tid >> 6, lane = tid & 63;
    int half = lane >> 5, fl = lane & 31;
    int i = blockIdx.x * NPB2 + w * 2 + half;
    if (i >= NN) return;
    float2 acc = gather_half(ylh, csrc, ptr[i], ptr[i + 1], fl);
    int f0 = fl * 2;
    float dv = dinv[i];
    float2 yrv = __half22float2(*(const __half2*)&yrh[(size_t)i * 64 + f0]);
    float b0 = (f0 < DOUT_FINAL) ? bl[f0] : 0.0f;
    float b1 = (f0 + 1 < DOUT_FINAL) ? bl[f0 + 1] : 0.0f;
    float vx = (f0 < DOUT_FINAL) ? acc.x * dv + yrv.x + b0 : -__builtin_inff();
    float vy = (f0 + 1 < DOUT_FINAL) ? acc.y * dv + yrv.y + b1 : -__builtin_inff();
    // width-32 reductions within the half-wave
    float mx = fmaxf(vx, vy);
    for (int o = 16; o; o >>= 1) mx = fmaxf(mx, __shfl_xor(mx, o, 32));
    float ex = ((f0 < DOUT_FINAL) ? expf(vx - mx) : 0.0f) +
               ((f0 + 1 < DOUT_FINAL) ? expf(vy - mx) : 0.0f);
    float s = ex;
    for (int o = 16; o; o >>= 1) s += __shfl_xor(s, o, 32);
    float ls = logf(s);
    if (f0 < DOUT_FINAL)     outp[(size_t)i * DOUT_FINAL + f0] = vx - mx - ls;
    if (f0 + 1 < DOUT_FINAL) outp[(size_t)i * DOUT_FINAL + f0 + 1] = vy - mx - ls;
}

// ---------------- launch ----------------

extern "C" void kernel_launch(void* const* d_in, const int* in_sizes, int n_in,
                              void* d_out, int out_size, void* d_ws, size_t ws_size,
                              hipStream_t stream) {
    const float* x    = (const float*)d_in[0];
    const int*   ei   = (const int*)d_in[1];
    const float* Win  = (const float*)d_in[2];
    const float* bin  = (const float*)d_in[3];
    const float* Wl0  = (const float*)d_in[4];
    const float* Wr0  = (const float*)d_in[5];
    const float* bl0  = (const float*)d_in[6];
    const float* Wl1  = (const float*)d_in[7];
    const float* Wr1  = (const float*)d_in[8];
    const float* bl1  = (const float*)d_in[9];
    const float* Wl2  = (const float*)d_in[10];
    const float* Wr2  = (const float*)d_in[11];
    const float* bl2  = (const float*)d_in[12];
    const float* Wl3  = (const float*)d_in[13];
    const float* Wr3  = (const float*)d_in[14];
    const float* bl3  = (const float*)d_in[15];
    float* out = (float*)d_out;

    const int* src = ei;
    const int* dst = ei + NE;

    size_t off = 0;
    auto alloc = [&](size_t bytes) -> void* {
        void* p = (char*)d_ws + off;
        off += (bytes + 255) & ~(size_t)255;
        return p;
    };
    int*    bkt    = (int*)alloc((size_t)2 * NBKT * 4);   // [bktCnt | bktCur]
    int*    bktPtr = (int*)alloc((size_t)(NBKT + 1) * 4);
    int2*   pairs  = (int2*)alloc((size_t)NE * 8);
    int*    cnt    = (int*)alloc((size_t)NN * 4);
    int*    ptr    = (int*)alloc((size_t)(NN + 1) * 4);
    float*  dinv   = (float*)alloc((size_t)NN * 4);
    int*    csrc   = (int*)alloc((size_t)NE * 4);
    int*    bsum   = (int*)alloc(512 * 4);
    __half* hinph  = (__half*)alloc((size_t)NN * 64 * 2);
    float*  xa     = (float*)alloc((size_t)NN * 64 * 4);
    float*  xb     = (float*)alloc((size_t)NN * 64 * 4);
    __half* ylh    = (__half*)alloc((size_t)NN * 64 * 2);
    __half* yrh    = (__half*)alloc((size_t)NN * 64 * 2);
    int*    bktCnt = bkt;
    int*    bktCur = bkt + NBKT;

    const int NB_NODE = (NN + 255) / 256;             // 391
    const int NB_AGG  = (NN + NPB2 - 1) / NPB2;       // 12500
    const int NB_GEMM = (NN + MT - 1) / MT;           // 782
    const int NB_SCAT = (NE + EB - 1) / EB;           // 293

    // ---- binned CSR build ----
    hipMemsetAsync(bkt, 0, (size_t)2 * NBKT * 4, stream);
    bucket_hist_k<<<512, 256, 0, stream>>>(dst, bktCnt);
    bscan_k<<<1, 512, 0, stream>>>(bktCnt, bktPtr);
    scatter_pairs_k<<<NB_SCAT, 256, 0, stream>>>(src, dst, bktPtr, bktCur, pairs);
    count_node_k<<<NBKT, 256, 0, stream>>>(pairs, bktPtr, cnt);
    scan1_k<<<NB_NODE, 256, 0, stream>>>(cnt, ptr, bsum, dinv);
    scan2_k<<<1, 512, 0, stream>>>(bsum, NB_NODE);
    scan3_k<<<NB_NODE, 256, 0, stream>>>(ptr, bsum);
    fill_bucket_k<<<NBKT, 256, 0, stream>>>(pairs, bktPtr, ptr, csrc);

    // ---- input projection ----
    gemm_in_k<<<NB_GEMM, 512, 0, stream>>>(x, Win, bin, hinph, xa);

    // layer 0: xa -> xb
    gemm_dual_k<<<NB_GEMM, 512, 0, stream>>>(xa, Wl0, Wr0, ylh, yrh, 64);
    aggregate_mid_k<<<NB_AGG, 256, 0, stream>>>(ylh, yrh, hinph, ptr, csrc, dinv, bl0, xb);
    // layer 1: xb -> xa
    gemm_dual_k<<<NB_GEMM, 512, 0, stream>>>(xb, Wl1, Wr1, ylh, yrh, 64);
    aggregate_mid_k<<<NB_AGG, 256, 0, stream>>>(ylh, yrh, hinph, ptr, csrc, dinv, bl1, xa);
    // layer 2: xa -> xb
    gemm_dual_k<<<NB_GEMM, 512, 0, stream>>>(xa, Wl2, Wr2, ylh, yrh, 64);
    aggregate_mid_k<<<NB_AGG, 256, 0, stream>>>(ylh, yrh, hinph, ptr, csrc, dinv, bl2, xb);
    // layer 3: xb -> out (fused log_softmax)
    gemm_dual_k<<<NB_GEMM, 512, 0, stream>>>(xb, Wl3, Wr3, ylh, yrh, 47);
    aggregate_final_k<<<NB_AGG, 256, 0, stream>>>(ylh, yrh, ptr, csrc, dinv, bl3, out);
}

// Round 19
// 343.674 us; speedup vs baseline: 1.2731x; 1.2731x over previous
//
#include <hip/hip_runtime.h>
#include <hip/hip_fp16.h>

#define NN 100000
#define NE 1200000
#define DIN 128
#define DH 64
#define DOUT_FINAL 47
#define NPB 4        // nodes per block in gather kernels
#define NBKT 391     // (NN + 255) >> 8  — bucket = dst >> 8 (256 nodes/bucket)
#define EB 4096      // edges per block in scatter_pairs_k

typedef _Float16 half8 __attribute__((ext_vector_type(8)));
typedef float floatx4 __attribute__((ext_vector_type(4)));

// ---------------- binned CSR build ----------------

__global__ void bucket_hist_k(const int* __restrict__ dst, int* __restrict__ bktCnt) {
    __shared__ int h[NBKT];
    int tid = threadIdx.x;
    for (int i = tid; i < NBKT; i += 256) h[i] = 0;
    __syncthreads();
    for (int e = blockIdx.x * 256 + tid; e < NE; e += gridDim.x * 256)
        atomicAdd(&h[dst[e] >> 8], 1);
    __syncthreads();
    for (int i = tid; i < NBKT; i += 256)
        if (h[i]) atomicAdd(&bktCnt[i], h[i]);
}

__global__ void bscan_k(const int* __restrict__ bktCnt, int* __restrict__ bktPtr) {
    __shared__ int s[512];
    int tid = threadIdx.x;
    int v = (tid < NBKT) ? bktCnt[tid] : 0;
    s[tid] = v;
    __syncthreads();
    for (int off = 1; off < 512; off <<= 1) {
        int t = (tid >= off) ? s[tid - off] : 0;
        __syncthreads();
        s[tid] += t;
        __syncthreads();
    }
    if (tid < NBKT) bktPtr[tid] = s[tid] - v;
    if (tid == 0) bktPtr[NBKT] = NE;
}

__global__ void scatter_pairs_k(const int* __restrict__ src, const int* __restrict__ dst,
                                const int* __restrict__ bktPtr, int* __restrict__ bktCur,
                                int2* __restrict__ pairs) {
    __shared__ int h[NBKT];
    __shared__ int base[NBKT];
    __shared__ int cur[NBKT];
    int tid = threadIdx.x;
    int e0 = blockIdx.x * EB;
    int e1 = e0 + EB < NE ? e0 + EB : NE;
    for (int i = tid; i < NBKT; i += 256) { h[i] = 0; cur[i] = 0; }
    __syncthreads();
    for (int e = e0 + tid; e < e1; e += 256)
        atomicAdd(&h[dst[e] >> 8], 1);
    __syncthreads();
    for (int i = tid; i < NBKT; i += 256) {
        int c = h[i];
        base[i] = bktPtr[i] + (c ? atomicAdd(&bktCur[i], c) : 0);
    }
    __syncthreads();
    for (int e = e0 + tid; e < e1; e += 256) {
        int d = dst[e];
        int b = d >> 8;
        int p = base[b] + atomicAdd(&cur[b], 1);
        pairs[p] = make_int2(src[e], d);
    }
}

__global__ void count_node_k(const int2* __restrict__ pairs, const int* __restrict__ bktPtr,
                             int* __restrict__ cnt) {
    __shared__ int h[256];
    int tid = threadIdx.x;
    int b = blockIdx.x;
    h[tid] = 0;
    __syncthreads();
    int e1 = bktPtr[b + 1];
    for (int e = bktPtr[b] + tid; e < e1; e += 256)
        atomicAdd(&h[pairs[e].y & 255], 1);
    __syncthreads();
    int node = (b << 8) + tid;
    if (node < NN) cnt[node] = h[tid];
}

__global__ void scan1_k(const int* __restrict__ cnt, int* __restrict__ ptr,
                        int* __restrict__ bsum, float* __restrict__ dinv) {
    __shared__ int s[256];
    int tid = threadIdx.x;
    int i = blockIdx.x * 256 + tid;
    int v = (i < NN) ? cnt[i] : 0;
    s[tid] = v;
    __syncthreads();
    for (int off = 1; off < 256; off <<= 1) {
        int t = (tid >= off) ? s[tid - off] : 0;
        __syncthreads();
        s[tid] += t;
        __syncthreads();
    }
    if (i < NN) {
        ptr[i] = s[tid] - v;
        dinv[i] = (v > 0) ? 1.0f / (float)v : 0.0f;
    }
    if (tid == 255) bsum[blockIdx.x] = s[255];
}

__global__ void scan2_k(int* __restrict__ bsum, int nb) {
    __shared__ int s[512];
    int tid = threadIdx.x;
    int v = (tid < nb) ? bsum[tid] : 0;
    s[tid] = v;
    __syncthreads();
    for (int off = 1; off < 512; off <<= 1) {
        int t = (tid >= off) ? s[tid - off] : 0;
        __syncthreads();
        s[tid] += t;
        __syncthreads();
    }
    if (tid < nb) bsum[tid] = s[tid] - v;
}

__global__ void scan3_k(int* __restrict__ ptr, const int* __restrict__ bsum) {
    int i = blockIdx.x * 256 + threadIdx.x;
    if (i < NN) ptr[i] += bsum[blockIdx.x];
    if (i == 0) ptr[NN] = NE;
}

__global__ void fill_bucket_k(const int2* __restrict__ pairs, const int* __restrict__ bktPtr,
                              const int* __restrict__ ptr, int* __restrict__ csrc) {
    __shared__ int cur[256];
    __shared__ int sptr[256];
    int tid = threadIdx.x;
    int b = blockIdx.x;
    cur[tid] = 0;
    int node = (b << 8) + tid;
    sptr[tid] = (node < NN) ? ptr[node] : 0;
    __syncthreads();
    int e1 = bktPtr[b + 1];
    for (int e = bktPtr[b] + tid; e < e1; e += 256) {
        int2 pr = pairs[e];
        int lo = pr.y & 255;
        int r = atomicAdd(&cur[lo], 1);
        csrc[sptr[lo] + r] = pr.x;
    }
}

// ---------------- fp32 -> fp16 conversions ----------------

__global__ void convert_x_k(const float* __restrict__ x, __half* __restrict__ xh) {
    int i = (blockIdx.x * 256 + threadIdx.x) * 8;
    if (i >= NN * DIN) return;
    float4 v0 = *(const float4*)&x[i];
    float4 v1 = *(const float4*)&x[i + 4];
    union { __half h[8]; uint4 u; } pk;
    pk.h[0] = __float2half(v0.x); pk.h[1] = __float2half(v0.y);
    pk.h[2] = __float2half(v0.z); pk.h[3] = __float2half(v0.w);
    pk.h[4] = __float2half(v1.x); pk.h[5] = __float2half(v1.y);
    pk.h[6] = __float2half(v1.z); pk.h[7] = __float2half(v1.w);
    *(uint4*)&xh[i] = pk.u;
}

// wh layout: [0,8192) = Win[64][128]; then 8 matrices of [64][64] zero-padded:
// order Wl0,Wr0,Wl1,Wr1,Wl2,Wr2,Wl3,Wr3 (Wl3/Wr3 rows 47..63 zeroed)
__global__ void convert_w_k(const float* __restrict__ Win,
                            const float* __restrict__ Wl0, const float* __restrict__ Wr0,
                            const float* __restrict__ Wl1, const float* __restrict__ Wr1,
                            const float* __restrict__ Wl2, const float* __restrict__ Wr2,
                            const float* __restrict__ Wl3, const float* __restrict__ Wr3,
                            __half* __restrict__ wh) {
    int id = blockIdx.x * 256 + threadIdx.x;
    if (id >= 8192 + 8 * 4096) return;
    float v;
    if (id < 8192) {
        v = Win[id];
    } else {
        int q = id - 8192;
        int mi = q >> 12;
        int local = q & 4095;
        int r = local >> 6, c = local & 63;
        const float* srcs[8] = {Wl0, Wr0, Wl1, Wr1, Wl2, Wr2, Wl3, Wr3};
        int dout = (mi >= 6) ? DOUT_FINAL : 64;
        v = (r < dout) ? srcs[mi][r * 64 + c] : 0.0f;
    }
    wh[id] = __float2half(v);
}

// ---------------- MFMA fp16 GEMMs ----------------
// D = A*B, v_mfma_f32_16x16x32_f16. Lane l: A[l&15][(l>>4)*8+j], B[(l>>4)*8+j][l&15];
// C/D: col=l&15, row=(l>>4)*4+j. Block: 256 thr = 4 waves, tile 128(M)x64(N);
// wave handles 32 rows (2 M-tiles) x 4 N-tiles.

// input projection: K=128; out hinp(fp16) = A@Win^T + bias ; xa(fp16) = relu
__global__ __launch_bounds__(256) void gemm_in_mfma(const _Float16* __restrict__ Xh,
                                                    const _Float16* __restrict__ Wh,
                                                    const float* __restrict__ bias,
                                                    __half* __restrict__ hinph,
                                                    __half* __restrict__ xah) {
    int wave = threadIdx.x >> 6, lane = threadIdx.x & 63;
    int lr = lane & 15, kg = lane >> 4;
    int m0 = blockIdx.x * 128 + wave * 32;
    floatx4 acc[2][4];
    #pragma unroll
    for (int mt = 0; mt < 2; ++mt)
        #pragma unroll
        for (int nt = 0; nt < 4; ++nt) acc[mt][nt] = (floatx4){0.f, 0.f, 0.f, 0.f};
    half8 az = {};
    #pragma unroll
    for (int kc = 0; kc < 4; ++kc) {
        half8 a[2];
        #pragma unroll
        for (int mt = 0; mt < 2; ++mt) {
            int m = m0 + mt * 16 + lr;
            a[mt] = (m < NN) ? *(const half8*)&Xh[(size_t)m * 128 + kc * 32 + kg * 8] : az;
        }
        #pragma unroll
        for (int nt = 0; nt < 4; ++nt) {
            half8 b = *(const half8*)&Wh[(size_t)(nt * 16 + lr) * 128 + kc * 32 + kg * 8];
            #pragma unroll
            for (int mt = 0; mt < 2; ++mt)
                acc[mt][nt] = __builtin_amdgcn_mfma_f32_16x16x32_f16(a[mt], b, acc[mt][nt], 0, 0, 0);
        }
    }
    #pragma unroll
    for (int mt = 0; mt < 2; ++mt)
        #pragma unroll
        for (int nt = 0; nt < 4; ++nt) {
            int n = nt * 16 + lr;
            float bv = bias[n];
            #pragma unroll
            for (int j = 0; j < 4; ++j) {
                int m = m0 + mt * 16 + kg * 4 + j;
                if (m < NN) {
                    float v = acc[mt][nt][j] + bv;
                    hinph[(size_t)m * 64 + n] = __float2half(v);
                    xah[(size_t)m * 64 + n] = __float2half(fmaxf(v, 0.0f));
                }
            }
        }
}

// dual layer GEMM: K=64; ylh = A@Wl^T, yrh = A@Wr^T (fp16 out)
__global__ __launch_bounds__(256) void gemm_dual_mfma(const _Float16* __restrict__ Xh,
                                                      const _Float16* __restrict__ Wlh,
                                                      const _Float16* __restrict__ Wrh,
                                                      __half* __restrict__ ylh,
                                                      __half* __restrict__ yrh) {
    int wave = threadIdx.x >> 6, lane = threadIdx.x & 63;
    int lr = lane & 15, kg = lane >> 4;
    int m0 = blockIdx.x * 128 + wave * 32;
    floatx4 accL[2][4], accR[2][4];
    #pragma unroll
    for (int mt = 0; mt < 2; ++mt)
        #pragma unroll
        for (int nt = 0; nt < 4; ++nt) {
            accL[mt][nt] = (floatx4){0.f, 0.f, 0.f, 0.f};
            accR[mt][nt] = (floatx4){0.f, 0.f, 0.f, 0.f};
        }
    half8 az = {};
    #pragma unroll
    for (int kc = 0; kc < 2; ++kc) {
        half8 a[2];
        #pragma unroll
        for (int mt = 0; mt < 2; ++mt) {
            int m = m0 + mt * 16 + lr;
            a[mt] = (m < NN) ? *(const half8*)&Xh[(size_t)m * 64 + kc * 32 + kg * 8] : az;
        }
        #pragma unroll
        for (int nt = 0; nt < 4; ++nt) {
            half8 bl = *(const half8*)&Wlh[(size_t)(nt * 16 + lr) * 64 + kc * 32 + kg * 8];
            half8 br = *(const half8*)&Wrh[(size_t)(nt * 16 + lr) * 64 + kc * 32 + kg * 8];
            #pragma unroll
            for (int mt = 0; mt < 2; ++mt) {
                accL[mt][nt] = __builtin_amdgcn_mfma_f32_16x16x32_f16(a[mt], bl, accL[mt][nt], 0, 0, 0);
                accR[mt][nt] = __builtin_amdgcn_mfma_f32_16x16x32_f16(a[mt], br, accR[mt][nt], 0, 0, 0);
            }
        }
    }
    #pragma unroll
    for (int mt = 0; mt < 2; ++mt)
        #pragma unroll
        for (int nt = 0; nt < 4; ++nt) {
            int n = nt * 16 + lr;
            #pragma unroll
            for (int j = 0; j < 4; ++j) {
                int m = m0 + mt * 16 + kg * 4 + j;
                if (m < NN) {
                    ylh[(size_t)m * 64 + n] = __float2half(accL[mt][nt][j]);
                    yrh[(size_t)m * 64 + n] = __float2half(accR[mt][nt][j]);
                }
            }
        }
}

// ---------------- gather core: 2 edges per wave, half2 loads (round-12/16 proven) ----------------

__device__ __forceinline__ float2 gather_sum2(const __half* __restrict__ ylh,
                                              const int* __restrict__ csrc,
                                              int eb, int ee, int lane) {
    int half = lane >> 5;
    int fo = (lane & 31) * 4;                // byte offset of this lane's half2
    const char* base = (const char*)ylh;
    float accx = 0.0f, accy = 0.0f;
    for (int e0 = eb; e0 < ee; e0 += 64) {
        int rem = ee - e0;
        int m = rem < 64 ? rem : 64;
        int sv = (lane < m) ? csrc[e0 + lane] : 0;   // coalesced edge prefetch
        int j = 0;
        for (; j + 8 <= m; j += 8) {
            int sA = __shfl(sv, j + 0 + half);
            int sB = __shfl(sv, j + 2 + half);
            int sC = __shfl(sv, j + 4 + half);
            int sD = __shfl(sv, j + 6 + half);
            float2 a = __half22float2(*(const __half2*)(base + (sA * 128 + fo)));
            float2 b = __half22float2(*(const __half2*)(base + (sB * 128 + fo)));
            float2 c = __half22float2(*(const __half2*)(base + (sC * 128 + fo)));
            float2 d = __half22float2(*(const __half2*)(base + (sD * 128 + fo)));
            accx += (a.x + b.x) + (c.x + d.x);
            accy += (a.y + b.y) + (c.y + d.y);
        }
        for (; j + 2 <= m; j += 2) {
            int s = __shfl(sv, j + half);
            float2 a = __half22float2(*(const __half2*)(base + (s * 128 + fo)));
            accx += a.x;
            accy += a.y;
        }
        if (j < m) {
            int s = __shfl(sv, j);
            if (half == 0) {
                float2 a = __half22float2(*(const __half2*)(base + (s * 128 + fo)));
                accx += a.x;
                accy += a.y;
            }
        }
    }
    accx += __shfl_xor(accx, 32);
    accy += __shfl_xor(accy, 32);
    return make_float2(accx, accy);        // duplicated across halves
}

// ---------------- mid-layer aggregate: relu + residual; writes fp16 activation ----------------

__global__ void aggregate_mid_k(const __half* __restrict__ ylh, const __half* __restrict__ yrh,
                                const __half* __restrict__ hinph,
                                const int* __restrict__ ptr, const int* __restrict__ csrc,
                                const float* __restrict__ dinv, const float* __restrict__ bl,
                                __half* __restrict__ outp) {
    int tid = threadIdx.x;
    int w = tid >> 6, lane = tid & 63;
    int i = blockIdx.x * NPB + w;
    if (i >= NN) return;
    float2 acc = gather_sum2(ylh, csrc, ptr[i], ptr[i + 1], lane);
    int half = lane >> 5;
    int f0 = (lane & 31) * 2;
    float dv = dinv[i];
    float2 yrv = __half22float2(*(const __half2*)&yrh[(size_t)i * 64 + f0]);
    float2 blv = *(const float2*)&bl[f0];
    float2 hv = __half22float2(*(const __half2*)&hinph[(size_t)i * 64 + f0]);
    float rx = fmaxf(acc.x * dv + yrv.x + blv.x, 0.0f) + 0.2f * hv.x;
    float ry = fmaxf(acc.y * dv + yrv.y + blv.y, 0.0f) + 0.2f * hv.y;
    if (half == 0) {
        __half2 hv2;
        hv2.x = __float2half(rx);
        hv2.y = __float2half(ry);
        *(__half2*)&outp[(size_t)i * 64 + f0] = hv2;
    }
}

// ---------------- final aggregate fused with log_softmax ----------------

__global__ void aggregate_final_k(const __half* __restrict__ ylh, const __half* __restrict__ yrh,
                                  const int* __restrict__ ptr, const int* __restrict__ csrc,
                                  const float* __restrict__ dinv, const float* __restrict__ bl,
                                  float* __restrict__ outp) {
    int tid = threadIdx.x;
    int w = tid >> 6, lane = tid & 63;
    int i = blockIdx.x * NPB + w;
    if (i >= NN) return;
    float2 acc = gather_sum2(ylh, csrc, ptr[i], ptr[i + 1], lane);
    int half = lane >> 5;
    int f0 = (lane & 31) * 2;
    float dv = dinv[i];
    float2 yrv = __half22float2(*(const __half2*)&yrh[(size_t)i * 64 + f0]);
    float b0 = (f0 < DOUT_FINAL) ? bl[f0] : 0.0f;
    float b1 = (f0 + 1 < DOUT_FINAL) ? bl[f0 + 1] : 0.0f;
    float vx = (f0 < DOUT_FINAL) ? acc.x * dv + yrv.x + b0 : -__builtin_inff();
    float vy = (f0 + 1 < DOUT_FINAL) ? acc.y * dv + yrv.y + b1 : -__builtin_inff();
    float mx = fmaxf(vx, vy);
    for (int o = 16; o; o >>= 1) mx = fmaxf(mx, __shfl_xor(mx, o));
    float ex = ((f0 < DOUT_FINAL) ? expf(vx - mx) : 0.0f) +
               ((f0 + 1 < DOUT_FINAL) ? expf(vy - mx) : 0.0f);
    float s = ex;
    for (int o = 16; o; o >>= 1) s += __shfl_xor(s, o);
    float ls = logf(s);
    if (half == 0) {
        if (f0 < DOUT_FINAL)     outp[(size_t)i * DOUT_FINAL + f0] = vx - mx - ls;
        if (f0 + 1 < DOUT_FINAL) outp[(size_t)i * DOUT_FINAL + f0 + 1] = vy - mx - ls;
    }
}

// ---------------- launch ----------------

extern "C" void kernel_launch(void* const* d_in, const int* in_sizes, int n_in,
                              void* d_out, int out_size, void* d_ws, size_t ws_size,
                              hipStream_t stream) {
    const float* x    = (const float*)d_in[0];
    const int*   ei   = (const int*)d_in[1];
    const float* Win  = (const float*)d_in[2];
    const float* bin  = (const float*)d_in[3];
    const float* Wl0  = (const float*)d_in[4];
    const float* Wr0  = (const float*)d_in[5];
    const float* bl0  = (const float*)d_in[6];
    const float* Wl1  = (const float*)d_in[7];
    const float* Wr1  = (const float*)d_in[8];
    const float* bl1  = (const float*)d_in[9];
    const float* Wl2  = (const float*)d_in[10];
    const float* Wr2  = (const float*)d_in[11];
    const float* bl2  = (const float*)d_in[12];
    const float* Wl3  = (const float*)d_in[13];
    const float* Wr3  = (const float*)d_in[14];
    const float* bl3  = (const float*)d_in[15];
    float* out = (float*)d_out;

    const int* src = ei;
    const int* dst = ei + NE;

    size_t off = 0;
    auto alloc = [&](size_t bytes) -> void* {
        void* p = (char*)d_ws + off;
        off += (bytes + 255) & ~(size_t)255;
        return p;
    };
    int*    bkt    = (int*)alloc((size_t)2 * NBKT * 4);   // [bktCnt | bktCur]
    int*    bktPtr = (int*)alloc((size_t)(NBKT + 1) * 4);
    int2*   pairs  = (int2*)alloc((size_t)NE * 8);
    int*    cnt    = (int*)alloc((size_t)NN * 4);
    int*    ptr    = (int*)alloc((size_t)(NN + 1) * 4);
    float*  dinv   = (float*)alloc((size_t)NN * 4);
    int*    csrc   = (int*)alloc((size_t)NE * 4);
    int*    bsum   = (int*)alloc(512 * 4);
    __half* xh     = (__half*)alloc((size_t)NN * 128 * 2);
    __half* wh     = (__half*)alloc((size_t)(8192 + 8 * 4096) * 2);
    __half* hinph  = (__half*)alloc((size_t)NN * 64 * 2);
    __half* xah    = (__half*)alloc((size_t)NN * 64 * 2);
    __half* xbh    = (__half*)alloc((size_t)NN * 64 * 2);
    __half* ylh    = (__half*)alloc((size_t)NN * 64 * 2);
    __half* yrh    = (__half*)alloc((size_t)NN * 64 * 2);
    int*    bktCnt = bkt;
    int*    bktCur = bkt + NBKT;

    __half* Winh = wh;
    __half* Wl0h = wh + 8192;
    __half* Wr0h = Wl0h + 4096;
    __half* Wl1h = Wr0h + 4096;
    __half* Wr1h = Wl1h + 4096;
    __half* Wl2h = Wr1h + 4096;
    __half* Wr2h = Wl2h + 4096;
    __half* Wl3h = Wr2h + 4096;
    __half* Wr3h = Wl3h + 4096;

    const int NB_NODE = (NN + 255) / 256;             // 391
    const int NB_AGG  = (NN + NPB - 1) / NPB;         // 25000
    const int NB_GEMM = (NN + 127) / 128;             // 782
    const int NB_SCAT = (NE + EB - 1) / EB;           // 293
    const int NB_XC   = (NN * DIN / 8 + 255) / 256;   // 6250
    const int NB_WC   = (8192 + 8 * 4096 + 255) / 256;

    // ---- conversions ----
    convert_x_k<<<NB_XC, 256, 0, stream>>>(x, xh);
    convert_w_k<<<NB_WC, 256, 0, stream>>>(Win, Wl0, Wr0, Wl1, Wr1, Wl2, Wr2, Wl3, Wr3, wh);

    // ---- binned CSR build ----
    hipMemsetAsync(bkt, 0, (size_t)2 * NBKT * 4, stream);
    bucket_hist_k<<<512, 256, 0, stream>>>(dst, bktCnt);
    bscan_k<<<1, 512, 0, stream>>>(bktCnt, bktPtr);
    scatter_pairs_k<<<NB_SCAT, 256, 0, stream>>>(src, dst, bktPtr, bktCur, pairs);
    count_node_k<<<NBKT, 256, 0, stream>>>(pairs, bktPtr, cnt);
    scan1_k<<<NB_NODE, 256, 0, stream>>>(cnt, ptr, bsum, dinv);
    scan2_k<<<1, 512, 0, stream>>>(bsum, NB_NODE);
    scan3_k<<<NB_NODE, 256, 0, stream>>>(ptr, bsum);
    fill_bucket_k<<<NBKT, 256, 0, stream>>>(pairs, bktPtr, ptr, csrc);

    // ---- input projection (MFMA) ----
    gemm_in_mfma<<<NB_GEMM, 256, 0, stream>>>((const _Float16*)xh, (const _Float16*)Winh, bin, hinph, xah);

    // layer 0: xah -> xbh
    gemm_dual_mfma<<<NB_GEMM, 256, 0, stream>>>((const _Float16*)xah, (const _Float16*)Wl0h, (const _Float16*)Wr0h, ylh, yrh);
    aggregate_mid_k<<<NB_AGG, 256, 0, stream>>>(ylh, yrh, hinph, ptr, csrc, dinv, bl0, xbh);
    // layer 1: xbh -> xah
    gemm_dual_mfma<<<NB_GEMM, 256, 0, stream>>>((const _Float16*)xbh, (const _Float16*)Wl1h, (const _Float16*)Wr1h, ylh, yrh);
    aggregate_mid_k<<<NB_AGG, 256, 0, stream>>>(ylh, yrh, hinph, ptr, csrc, dinv, bl1, xah);
    // layer 2: xah -> xbh
    gemm_dual_mfma<<<NB_GEMM, 256, 0, stream>>>((const _Float16*)xah, (const _Float16*)Wl2h, (const _Float16*)Wr2h, ylh, yrh);
    aggregate_mid_k<<<NB_AGG, 256, 0, stream>>>(ylh, yrh, hinph, ptr, csrc, dinv, bl2, xbh);
    // layer 3: xbh -> out (fused log_softmax)
    gemm_dual_mfma<<<NB_GEMM, 256, 0, stream>>>((const _Float16*)xbh, (const _Float16*)Wl3h, (const _Float16*)Wr3h, ylh, yrh);
    aggregate_final_k<<<NB_AGG, 256, 0, stream>>>(ylh, yrh, ptr, csrc, dinv, bl3, out);
}

// Round 22
// 316.052 us; speedup vs baseline: 1.3844x; 1.0874x over previous
//
#include <hip/hip_runtime.h>
#include <hip/hip_fp16.h>

#define NN 100000
#define NE 1200000
#define DIN 128
#define DH 64
#define DOUT_FINAL 47
#define NPB2 8       // nodes per block in gather kernels (2 per wave)
#define NBKT 391     // (NN + 255) >> 8  — bucket = dst >> 8 (256 nodes/bucket)
#define EB 4096      // edges per block in scatter_pairs_k

typedef _Float16 half8 __attribute__((ext_vector_type(8)));
typedef float floatx4 __attribute__((ext_vector_type(4)));

// ---------------- binned CSR build ----------------

__global__ void bucket_hist_k(const int* __restrict__ dst, int* __restrict__ bktCnt) {
    __shared__ int h[NBKT];
    int tid = threadIdx.x;
    for (int i = tid; i < NBKT; i += 256) h[i] = 0;
    __syncthreads();
    for (int e = blockIdx.x * 256 + tid; e < NE; e += gridDim.x * 256)
        atomicAdd(&h[dst[e] >> 8], 1);
    __syncthreads();
    for (int i = tid; i < NBKT; i += 256)
        if (h[i]) atomicAdd(&bktCnt[i], h[i]);
}

__global__ void bscan_k(const int* __restrict__ bktCnt, int* __restrict__ bktPtr) {
    __shared__ int s[512];
    int tid = threadIdx.x;
    int v = (tid < NBKT) ? bktCnt[tid] : 0;
    s[tid] = v;
    __syncthreads();
    for (int off = 1; off < 512; off <<= 1) {
        int t = (tid >= off) ? s[tid - off] : 0;
        __syncthreads();
        s[tid] += t;
        __syncthreads();
    }
    if (tid < NBKT) bktPtr[tid] = s[tid] - v;
    if (tid == 0) bktPtr[NBKT] = NE;
}

__global__ void scatter_pairs_k(const int* __restrict__ src, const int* __restrict__ dst,
                                const int* __restrict__ bktPtr, int* __restrict__ bktCur,
                                int2* __restrict__ pairs) {
    __shared__ int h[NBKT];
    __shared__ int base[NBKT];
    __shared__ int cur[NBKT];
    int tid = threadIdx.x;
    int e0 = blockIdx.x * EB;
    int e1 = e0 + EB < NE ? e0 + EB : NE;
    for (int i = tid; i < NBKT; i += 256) { h[i] = 0; cur[i] = 0; }
    __syncthreads();
    for (int e = e0 + tid; e < e1; e += 256)
        atomicAdd(&h[dst[e] >> 8], 1);
    __syncthreads();
    for (int i = tid; i < NBKT; i += 256) {
        int c = h[i];
        base[i] = bktPtr[i] + (c ? atomicAdd(&bktCur[i], c) : 0);
    }
    __syncthreads();
    for (int e = e0 + tid; e < e1; e += 256) {
        int d = dst[e];
        int b = d >> 8;
        int p = base[b] + atomicAdd(&cur[b], 1);
        pairs[p] = make_int2(src[e], d);
    }
}

__global__ void count_node_k(const int2* __restrict__ pairs, const int* __restrict__ bktPtr,
                             int* __restrict__ cnt) {
    __shared__ int h[256];
    int tid = threadIdx.x;
    int b = blockIdx.x;
    h[tid] = 0;
    __syncthreads();
    int e1 = bktPtr[b + 1];
    for (int e = bktPtr[b] + tid; e < e1; e += 256)
        atomicAdd(&h[pairs[e].y & 255], 1);
    __syncthreads();
    int node = (b << 8) + tid;
    if (node < NN) cnt[node] = h[tid];
}

__global__ void scan1_k(const int* __restrict__ cnt, int* __restrict__ ptr,
                        int* __restrict__ bsum, float* __restrict__ dinv) {
    __shared__ int s[256];
    int tid = threadIdx.x;
    int i = blockIdx.x * 256 + tid;
    int v = (i < NN) ? cnt[i] : 0;
    s[tid] = v;
    __syncthreads();
    for (int off = 1; off < 256; off <<= 1) {
        int t = (tid >= off) ? s[tid - off] : 0;
        __syncthreads();
        s[tid] += t;
        __syncthreads();
    }
    if (i < NN) {
        ptr[i] = s[tid] - v;
        dinv[i] = (v > 0) ? 1.0f / (float)v : 0.0f;
    }
    if (tid == 255) bsum[blockIdx.x] = s[255];
}

__global__ void scan2_k(int* __restrict__ bsum, int nb) {
    __shared__ int s[512];
    int tid = threadIdx.x;
    int v = (tid < nb) ? bsum[tid] : 0;
    s[tid] = v;
    __syncthreads();
    for (int off = 1; off < 512; off <<= 1) {
        int t = (tid >= off) ? s[tid - off] : 0;
        __syncthreads();
        s[tid] += t;
        __syncthreads();
    }
    if (tid < nb) bsum[tid] = s[tid] - v;
}

__global__ void scan3_k(int* __restrict__ ptr, const int* __restrict__ bsum) {
    int i = blockIdx.x * 256 + threadIdx.x;
    if (i < NN) ptr[i] += bsum[blockIdx.x];
    if (i == 0) ptr[NN] = NE;
}

__global__ void fill_bucket_k(const int2* __restrict__ pairs, const int* __restrict__ bktPtr,
                              const int* __restrict__ ptr, int* __restrict__ csrc) {
    __shared__ int cur[256];
    __shared__ int sptr[256];
    int tid = threadIdx.x;
    int b = blockIdx.x;
    cur[tid] = 0;
    int node = (b << 8) + tid;
    sptr[tid] = (node < NN) ? ptr[node] : 0;
    __syncthreads();
    int e1 = bktPtr[b + 1];
    for (int e = bktPtr[b] + tid; e < e1; e += 256) {
        int2 pr = pairs[e];
        int lo = pr.y & 255;
        int r = atomicAdd(&cur[lo], 1);
        csrc[sptr[lo] + r] = pr.x;
    }
}

// ---------------- fp32 -> fp16 conversions ----------------

__global__ void convert_x_k(const float* __restrict__ x, __half* __restrict__ xh) {
    int i = (blockIdx.x * 256 + threadIdx.x) * 8;
    if (i >= NN * DIN) return;
    float4 v0 = *(const float4*)&x[i];
    float4 v1 = *(const float4*)&x[i + 4];
    union { __half h[8]; uint4 u; } pk;
    pk.h[0] = __float2half(v0.x); pk.h[1] = __float2half(v0.y);
    pk.h[2] = __float2half(v0.z); pk.h[3] = __float2half(v0.w);
    pk.h[4] = __float2half(v1.x); pk.h[5] = __float2half(v1.y);
    pk.h[6] = __float2half(v1.z); pk.h[7] = __float2half(v1.w);
    *(uint4*)&xh[i] = pk.u;
}

// wh layout: [0,8192) = Win[64][128]; then 8 matrices of [64][64] zero-padded:
// order Wl0,Wr0,Wl1,Wr1,Wl2,Wr2,Wl3,Wr3 (Wl3/Wr3 rows 47..63 zeroed)
__global__ void convert_w_k(const float* __restrict__ Win,
                            const float* __restrict__ Wl0, const float* __restrict__ Wr0,
                            const float* __restrict__ Wl1, const float* __restrict__ Wr1,
                            const float* __restrict__ Wl2, const float* __restrict__ Wr2,
                            const float* __restrict__ Wl3, const float* __restrict__ Wr3,
                            __half* __restrict__ wh) {
    int id = blockIdx.x * 256 + threadIdx.x;
    if (id >= 8192 + 8 * 4096) return;
    float v;
    if (id < 8192) {
        v = Win[id];
    } else {
        int q = id - 8192;
        int mi = q >> 12;
        int local = q & 4095;
        int r = local >> 6, c = local & 63;
        const float* srcs[8] = {Wl0, Wr0, Wl1, Wr1, Wl2, Wr2, Wl3, Wr3};
        int dout = (mi >= 6) ? DOUT_FINAL : 64;
        v = (r < dout) ? srcs[mi][r * 64 + c] : 0.0f;
    }
    wh[id] = __float2half(v);
}

// ---------------- MFMA fp16 GEMMs (round-19 proven) ----------------

__global__ __launch_bounds__(256) void gemm_in_mfma(const _Float16* __restrict__ Xh,
                                                    const _Float16* __restrict__ Wh,
                                                    const float* __restrict__ bias,
                                                    __half* __restrict__ hinph,
                                                    __half* __restrict__ xah) {
    int wave = threadIdx.x >> 6, lane = threadIdx.x & 63;
    int lr = lane & 15, kg = lane >> 4;
    int m0 = blockIdx.x * 128 + wave * 32;
    floatx4 acc[2][4];
    #pragma unroll
    for (int mt = 0; mt < 2; ++mt)
        #pragma unroll
        for (int nt = 0; nt < 4; ++nt) acc[mt][nt] = (floatx4){0.f, 0.f, 0.f, 0.f};
    half8 az = {};
    #pragma unroll
    for (int kc = 0; kc < 4; ++kc) {
        half8 a[2];
        #pragma unroll
        for (int mt = 0; mt < 2; ++mt) {
            int m = m0 + mt * 16 + lr;
            a[mt] = (m < NN) ? *(const half8*)&Xh[(size_t)m * 128 + kc * 32 + kg * 8] : az;
        }
        #pragma unroll
        for (int nt = 0; nt < 4; ++nt) {
            half8 b = *(const half8*)&Wh[(size_t)(nt * 16 + lr) * 128 + kc * 32 + kg * 8];
            #pragma unroll
            for (int mt = 0; mt < 2; ++mt)
                acc[mt][nt] = __builtin_amdgcn_mfma_f32_16x16x32_f16(a[mt], b, acc[mt][nt], 0, 0, 0);
        }
    }
    #pragma unroll
    for (int mt = 0; mt < 2; ++mt)
        #pragma unroll
        for (int nt = 0; nt < 4; ++nt) {
            int n = nt * 16 + lr;
            float bv = bias[n];
            #pragma unroll
            for (int j = 0; j < 4; ++j) {
                int m = m0 + mt * 16 + kg * 4 + j;
                if (m < NN) {
                    float v = acc[mt][nt][j] + bv;
                    hinph[(size_t)m * 64 + n] = __float2half(v);
                    xah[(size_t)m * 64 + n] = __float2half(fmaxf(v, 0.0f));
                }
            }
        }
}

__global__ __launch_bounds__(256) void gemm_dual_mfma(const _Float16* __restrict__ Xh,
                                                      const _Float16* __restrict__ Wlh,
                                                      const _Float16* __restrict__ Wrh,
                                                      __half* __restrict__ ylh,
                                                      __half* __restrict__ yrh) {
    int wave = threadIdx.x >> 6, lane = threadIdx.x & 63;
    int lr = lane & 15, kg = lane >> 4;
    int m0 = blockIdx.x * 128 + wave * 32;
    floatx4 accL[2][4], accR[2][4];
    #pragma unroll
    for (int mt = 0; mt < 2; ++mt)
        #pragma unroll
        for (int nt = 0; nt < 4; ++nt) {
            accL[mt][nt] = (floatx4){0.f, 0.f, 0.f, 0.f};
            accR[mt][nt] = (floatx4){0.f, 0.f, 0.f, 0.f};
        }
    half8 az = {};
    #pragma unroll
    for (int kc = 0; kc < 2; ++kc) {
        half8 a[2];
        #pragma unroll
        for (int mt = 0; mt < 2; ++mt) {
            int m = m0 + mt * 16 + lr;
            a[mt] = (m < NN) ? *(const half8*)&Xh[(size_t)m * 64 + kc * 32 + kg * 8] : az;
        }
        #pragma unroll
        for (int nt = 0; nt < 4; ++nt) {
            half8 bl = *(const half8*)&Wlh[(size_t)(nt * 16 + lr) * 64 + kc * 32 + kg * 8];
            half8 br = *(const half8*)&Wrh[(size_t)(nt * 16 + lr) * 64 + kc * 32 + kg * 8];
            #pragma unroll
            for (int mt = 0; mt < 2; ++mt) {
                accL[mt][nt] = __builtin_amdgcn_mfma_f32_16x16x32_f16(a[mt], bl, accL[mt][nt], 0, 0, 0);
                accR[mt][nt] = __builtin_amdgcn_mfma_f32_16x16x32_f16(a[mt], br, accR[mt][nt], 0, 0, 0);
            }
        }
    }
    #pragma unroll
    for (int mt = 0; mt < 2; ++mt)
        #pragma unroll
        for (int nt = 0; nt < 4; ++nt) {
            int n = nt * 16 + lr;
            #pragma unroll
            for (int j = 0; j < 4; ++j) {
                int m = m0 + mt * 16 + kg * 4 + j;
                if (m < NN) {
                    ylh[(size_t)m * 64 + n] = __float2half(accL[mt][nt][j]);
                    yrh[(size_t)m * 64 + n] = __float2half(accR[mt][nt][j]);
                }
            }
        }
}

// ---------------- dual-node gather: 2 nodes per wave, phase-fused loops ----------------
// Per-node math/order identical to the proven single-node gather (bit-exact).
// Both csrc prefetches issued back-to-back; 8-edge bodies fused -> up to 8 row
// loads in flight. All loop guards wave-uniform -> shfls always full-wave.

__device__ __forceinline__ void gather_dual(const __half* __restrict__ ylh,
                                            const int* __restrict__ csrc,
                                            int eb0, int ee0, int eb1, int ee1,
                                            int lane, float2& r0, float2& r1) {
    int half = lane >> 5;
    int fo = (lane & 31) * 4;
    const char* base = (const char*)ylh;
    float a0x = 0.f, a0y = 0.f, a1x = 0.f, a1y = 0.f;

    auto body8 = [&](int sv, int j, float& ax, float& ay) {
        int sA = __shfl(sv, j + 0 + half);
        int sB = __shfl(sv, j + 2 + half);
        int sC = __shfl(sv, j + 4 + half);
        int sD = __shfl(sv, j + 6 + half);
        float2 a = __half22float2(*(const __half2*)(base + (sA * 128 + fo)));
        float2 b = __half22float2(*(const __half2*)(base + (sB * 128 + fo)));
        float2 c = __half22float2(*(const __half2*)(base + (sC * 128 + fo)));
        float2 d = __half22float2(*(const __half2*)(base + (sD * 128 + fo)));
        ax += (a.x + b.x) + (c.x + d.x);
        ay += (a.y + b.y) + (c.y + d.y);
    };
    auto body2 = [&](int sv, int j, float& ax, float& ay) {
        int s = __shfl(sv, j + half);
        float2 a = __half22float2(*(const __half2*)(base + (s * 128 + fo)));
        ax += a.x; ay += a.y;
    };
    auto body1 = [&](int sv, int j, float& ax, float& ay) {
        int s = __shfl(sv, j);           // full-wave shfl; guard only the use
        if (half == 0) {
            float2 a = __half22float2(*(const __half2*)(base + (s * 128 + fo)));
            ax += a.x; ay += a.y;
        }
    };

    int e0 = eb0, e1 = eb1;
    while (e0 < ee0 || e1 < ee1) {
        int m0 = 0, m1 = 0, sv0 = 0, sv1 = 0;
        if (e0 < ee0) {
            int rem = ee0 - e0; m0 = rem < 64 ? rem : 64;
            sv0 = (lane < m0) ? csrc[e0 + lane] : 0;
        }
        if (e1 < ee1) {
            int rem = ee1 - e1; m1 = rem < 64 ? rem : 64;
            sv1 = (lane < m1) ? csrc[e1 + lane] : 0;
        }
        int j0 = 0, j1 = 0;
        while (j0 + 8 <= m0 && j1 + 8 <= m1) {
            body8(sv0, j0, a0x, a0y);
            body8(sv1, j1, a1x, a1y);
            j0 += 8; j1 += 8;
        }
        while (j0 + 8 <= m0) { body8(sv0, j0, a0x, a0y); j0 += 8; }
        while (j1 + 8 <= m1) { body8(sv1, j1, a1x, a1y); j1 += 8; }
        while (j0 + 2 <= m0 && j1 + 2 <= m1) {
            body2(sv0, j0, a0x, a0y);
            body2(sv1, j1, a1x, a1y);
            j0 += 2; j1 += 2;
        }
        while (j0 + 2 <= m0) { body2(sv0, j0, a0x, a0y); j0 += 2; }
        while (j1 + 2 <= m1) { body2(sv1, j1, a1x, a1y); j1 += 2; }
        if (j0 < m0) body1(sv0, j0, a0x, a0y);
        if (j1 < m1) body1(sv1, j1, a1x, a1y);
        e0 += 64; e1 += 64;
    }
    a0x += __shfl_xor(a0x, 32); a0y += __shfl_xor(a0y, 32);
    a1x += __shfl_xor(a1x, 32); a1y += __shfl_xor(a1y, 32);
    r0 = make_float2(a0x, a0y);
    r1 = make_float2(a1x, a1y);
}

// ---------------- mid-layer aggregate (2 nodes/wave): relu + residual; fp16 out ----------------

__global__ void aggregate_mid_k(const __half* __restrict__ ylh, const __half* __restrict__ yrh,
                                const __half* __restrict__ hinph,
                                const int* __restrict__ ptr, const int* __restrict__ csrc,
                                const float* __restrict__ dinv, const float* __restrict__ bl,
                                __half* __restrict__ outp) {
    int tid = threadIdx.x;
    int w = tid >> 6, lane = tid & 63;
    int i0 = blockIdx.x * NPB2 + w * 2;
    int i1 = i0 + 1;
    if (i0 >= NN) return;
    int eb0 = ptr[i0], ee0 = ptr[i0 + 1];
    int eb1 = 0, ee1 = 0;
    if (i1 < NN) { eb1 = ptr[i1]; ee1 = ptr[i1 + 1]; }
    float2 acc0, acc1;
    gather_dual(ylh, csrc, eb0, ee0, eb1, ee1, lane, acc0, acc1);

    int half = lane >> 5;
    int f0 = (lane & 31) * 2;
    if (half == 0) {
        {
            float dv = dinv[i0];
            float2 yrv = __half22float2(*(const __half2*)&yrh[(size_t)i0 * 64 + f0]);
            float2 blv = *(const float2*)&bl[f0];
            float2 hv = __half22float2(*(const __half2*)&hinph[(size_t)i0 * 64 + f0]);
            __half2 hv2;
            hv2.x = __float2half(fmaxf(acc0.x * dv + yrv.x + blv.x, 0.0f) + 0.2f * hv.x);
            hv2.y = __float2half(fmaxf(acc0.y * dv + yrv.y + blv.y, 0.0f) + 0.2f * hv.y);
            *(__half2*)&outp[(size_t)i0 * 64 + f0] = hv2;
        }
        if (i1 < NN) {
            float dv = dinv[i1];
            float2 yrv = __half22float2(*(const __half2*)&yrh[(size_t)i1 * 64 + f0]);
            float2 blv = *(const float2*)&bl[f0];
            float2 hv = __half22float2(*(const __half2*)&hinph[(size_t)i1 * 64 + f0]);
            __half2 hv2;
            hv2.x = __float2half(fmaxf(acc1.x * dv + yrv.x + blv.x, 0.0f) + 0.2f * hv.x);
            hv2.y = __float2half(fmaxf(acc1.y * dv + yrv.y + blv.y, 0.0f) + 0.2f * hv.y);
            *(__half2*)&outp[(size_t)i1 * 64 + f0] = hv2;
        }
    }
}

// ---------------- final aggregate (2 nodes/wave) fused with log_softmax ----------------

__global__ void aggregate_final_k(const __half* __restrict__ ylh, const __half* __restrict__ yrh,
                                  const int* __restrict__ ptr, const int* __restrict__ csrc,
                                  const float* __restrict__ dinv, const float* __restrict__ bl,
                                  float* __restrict__ outp) {
    int tid = threadIdx.x;
    int w = tid >> 6, lane = tid & 63;
    int i0 = blockIdx.x * NPB2 + w * 2;
    int i1 = i0 + 1;
    if (i0 >= NN) return;
    int eb0 = ptr[i0], ee0 = ptr[i0 + 1];
    int eb1 = 0, ee1 = 0;
    if (i1 < NN) { eb1 = ptr[i1]; ee1 = ptr[i1 + 1]; }
    float2 acc0, acc1;
    gather_dual(ylh, csrc, eb0, ee0, eb1, ee1, lane, acc0, acc1);

    int half = lane >> 5;
    int f0 = (lane & 31) * 2;
    float b0 = (f0 < DOUT_FINAL) ? bl[f0] : 0.0f;
    float b1 = (f0 + 1 < DOUT_FINAL) ? bl[f0 + 1] : 0.0f;

    // node 0
    {
        float dv = dinv[i0];
        float2 yrv = __half22float2(*(const __half2*)&yrh[(size_t)i0 * 64 + f0]);
        float vx = (f0 < DOUT_FINAL) ? acc0.x * dv + yrv.x + b0 : -__builtin_inff();
        float vy = (f0 + 1 < DOUT_FINAL) ? acc0.y * dv + yrv.y + b1 : -__builtin_inff();
        float mx = fmaxf(vx, vy);
        for (int o = 16; o; o >>= 1) mx = fmaxf(mx, __shfl_xor(mx, o));
        float ex = ((f0 < DOUT_FINAL) ? expf(vx - mx) : 0.0f) +
                   ((f0 + 1 < DOUT_FINAL) ? expf(vy - mx) : 0.0f);
        float s = ex;
        for (int o = 16; o; o >>= 1) s += __shfl_xor(s, o);
        float ls = logf(s);
        if (half == 0) {
            if (f0 < DOUT_FINAL)     outp[(size_t)i0 * DOUT_FINAL + f0] = vx - mx - ls;
            if (f0 + 1 < DOUT_FINAL) outp[(size_t)i0 * DOUT_FINAL + f0 + 1] = vy - mx - ls;
        }
    }
    // node 1
    if (i1 < NN) {
        float dv = dinv[i1];
        float2 yrv = __half22float2(*(const __half2*)&yrh[(size_t)i1 * 64 + f0]);
        float vx = (f0 < DOUT_FINAL) ? acc1.x * dv + yrv.x + b0 : -__builtin_inff();
        float vy = (f0 + 1 < DOUT_FINAL) ? acc1.y * dv + yrv.y + b1 : -__builtin_inff();
        float mx = fmaxf(vx, vy);
        for (int o = 16; o; o >>= 1) mx = fmaxf(mx, __shfl_xor(mx, o));
        float ex = ((f0 < DOUT_FINAL) ? expf(vx - mx) : 0.0f) +
                   ((f0 + 1 < DOUT_FINAL) ? expf(vy - mx) : 0.0f);
        float s = ex;
        for (int o = 16; o; o >>= 1) s += __shfl_xor(s, o);
        float ls = logf(s);
        if (half == 0) {
            if (f0 < DOUT_FINAL)     outp[(size_t)i1 * DOUT_FINAL + f0] = vx - mx - ls;
            if (f0 + 1 < DOUT_FINAL) outp[(size_t)i1 * DOUT_FINAL + f0 + 1] = vy - mx - ls;
        }
    }
}

// ---------------- launch ----------------

extern "C" void kernel_launch(void* const* d_in, const int* in_sizes, int n_in,
                              void* d_out, int out_size, void* d_ws, size_t ws_size,
                              hipStream_t stream) {
    const float* x    = (const float*)d_in[0];
    const int*   ei   = (const int*)d_in[1];
    const float* Win  = (const float*)d_in[2];
    const float* bin  = (const float*)d_in[3];
    const float* Wl0  = (const float*)d_in[4];
    const float* Wr0  = (const float*)d_in[5];
    const float* bl0  = (const float*)d_in[6];
    const float* Wl1  = (const float*)d_in[7];
    const float* Wr1  = (const float*)d_in[8];
    const float* bl1  = (const float*)d_in[9];
    const float* Wl2  = (const float*)d_in[10];
    const float* Wr2  = (const float*)d_in[11];
    const float* bl2  = (const float*)d_in[12];
    const float* Wl3  = (const float*)d_in[13];
    const float* Wr3  = (const float*)d_in[14];
    const float* bl3  = (const float*)d_in[15];
    float* out = (float*)d_out;

    const int* src = ei;
    const int* dst = ei + NE;

    size_t off = 0;
    auto alloc = [&](size_t bytes) -> void* {
        void* p = (char*)d_ws + off;
        off += (bytes + 255) & ~(size_t)255;
        return p;
    };
    int*    bkt    = (int*)alloc((size_t)2 * NBKT * 4);   // [bktCnt | bktCur]
    int*    bktPtr = (int*)alloc((size_t)(NBKT + 1) * 4);
    int2*   pairs  = (int2*)alloc((size_t)NE * 8);
    int*    cnt    = (int*)alloc((size_t)NN * 4);
    int*    ptr    = (int*)alloc((size_t)(NN + 1) * 4);
    float*  dinv   = (float*)alloc((size_t)NN * 4);
    int*    csrc   = (int*)alloc((size_t)NE * 4);
    int*    bsum   = (int*)alloc(512 * 4);
    __half* xh     = (__half*)alloc((size_t)NN * 128 * 2);
    __half* wh     = (__half*)alloc((size_t)(8192 + 8 * 4096) * 2);
    __half* hinph  = (__half*)alloc((size_t)NN * 64 * 2);
    __half* xah    = (__half*)alloc((size_t)NN * 64 * 2);
    __half* xbh    = (__half*)alloc((size_t)NN * 64 * 2);
    __half* ylh    = (__half*)alloc((size_t)NN * 64 * 2);
    __half* yrh    = (__half*)alloc((size_t)NN * 64 * 2);
    int*    bktCnt = bkt;
    int*    bktCur = bkt + NBKT;

    __half* Winh = wh;
    __half* Wl0h = wh + 8192;
    __half* Wr0h = Wl0h + 4096;
    __half* Wl1h = Wr0h + 4096;
    __half* Wr1h = Wl1h + 4096;
    __half* Wl2h = Wr1h + 4096;
    __half* Wr2h = Wl2h + 4096;
    __half* Wl3h = Wr2h + 4096;
    __half* Wr3h = Wl3h + 4096;

    const int NB_NODE = (NN + 255) / 256;             // 391
    const int NB_AGG  = (NN + NPB2 - 1) / NPB2;       // 12500
    const int NB_GEMM = (NN + 127) / 128;             // 782
    const int NB_SCAT = (NE + EB - 1) / EB;           // 293
    const int NB_XC   = (NN * DIN / 8 + 255) / 256;   // 6250
    const int NB_WC   = (8192 + 8 * 4096 + 255) / 256;

    // ---- conversions ----
    convert_x_k<<<NB_XC, 256, 0, stream>>>(x, xh);
    convert_w_k<<<NB_WC, 256, 0, stream>>>(Win, Wl0, Wr0, Wl1, Wr1, Wl2, Wr2, Wl3, Wr3, wh);

    // ---- binned CSR build ----
    hipMemsetAsync(bkt, 0, (size_t)2 * NBKT * 4, stream);
    bucket_hist_k<<<512, 256, 0, stream>>>(dst, bktCnt);
    bscan_k<<<1, 512, 0, stream>>>(bktCnt, bktPtr);
    scatter_pairs_k<<<NB_SCAT, 256, 0, stream>>>(src, dst, bktPtr, bktCur, pairs);
    count_node_k<<<NBKT, 256, 0, stream>>>(pairs, bktPtr, cnt);
    scan1_k<<<NB_NODE, 256, 0, stream>>>(cnt, ptr, bsum, dinv);
    scan2_k<<<1, 512, 0, stream>>>(bsum, NB_NODE);
    scan3_k<<<NB_NODE, 256, 0, stream>>>(ptr, bsum);
    fill_bucket_k<<<NBKT, 256, 0, stream>>>(pairs, bktPtr, ptr, csrc);

    // ---- input projection (MFMA) ----
    gemm_in_mfma<<<NB_GEMM, 256, 0, stream>>>((const _Float16*)xh, (const _Float16*)Winh, bin, hinph, xah);

    // layer 0: xah -> xbh
    gemm_dual_mfma<<<NB_GEMM, 256, 0, stream>>>((const _Float16*)xah, (const _Float16*)Wl0h, (const _Float16*)Wr0h, ylh, yrh);
    aggregate_mid_k<<<NB_AGG, 256, 0, stream>>>(ylh, yrh, hinph, ptr, csrc, dinv, bl0, xbh);
    // layer 1: xbh -> xah
    gemm_dual_mfma<<<NB_GEMM, 256, 0, stream>>>((const _Float16*)xbh, (const _Float16*)Wl1h, (const _Float16*)Wr1h, ylh, yrh);
    aggregate_mid_k<<<NB_AGG, 256, 0, stream>>>(ylh, yrh, hinph, ptr, csrc, dinv, bl1, xah);
    // layer 2: xah -> xbh
    gemm_dual_mfma<<<NB_GEMM, 256, 0, stream>>>((const _Float16*)xah, (const _Float16*)Wl2h, (const _Float16*)Wr2h, ylh, yrh);
    aggregate_mid_k<<<NB_AGG, 256, 0, stream>>>(ylh, yrh, hinph, ptr, csrc, dinv, bl2, xbh);
    // layer 3: xbh -> out (fused log_softmax)
    gemm_dual_mfma<<<NB_GEMM, 256, 0, stream>>>((const _Float16*)xbh, (const _Float16*)Wl3h, (const _Float16*)Wr3h, ylh, yrh);
    aggregate_final_k<<<NB_AGG, 256, 0, stream>>>(ylh, yrh, ptr, csrc, dinv, bl3, out);
}